// Round 9
// baseline (372.750 us; speedup 1.0000x reference)
//
#include <hip/hip_runtime.h>
#include <hip/hip_bf16.h>

namespace {

constexpr int T = 200;

typedef float f32x4 __attribute__((ext_vector_type(4)));
typedef short bf16x8 __attribute__((ext_vector_type(8)));

__device__ __forceinline__ short f2bf(float f) {
  __hip_bfloat16 h = __float2bfloat16(f);  // RNE; pairs fuse to v_cvt_pk_bf16_f32
  return __builtin_bit_cast(short, h);
}
__device__ __forceinline__ float bf2f(short s) {
  return __uint_as_float(((unsigned)(unsigned short)s) << 16);
}

template <int CTRL>
__device__ __forceinline__ float dpp_add(float x) {
  int y = __builtin_amdgcn_update_dpp(0, __float_as_int(x), CTRL, 0xF, 0xF, true);
  return x + __int_as_float(y);
}
__device__ __forceinline__ float sum16(float x) {
  x = dpp_add<0x121>(x); x = dpp_add<0x122>(x);   // row_ror 1,2,4,8
  x = dpp_add<0x124>(x); x = dpp_add<0x128>(x);
  return x;
}

__device__ __forceinline__ void async_cp16(const void* g, void* l) {
  __builtin_amdgcn_global_load_lds((__attribute__((address_space(1))) void*)g,
                                   (__attribute__((address_space(3))) void*)l, 16, 0, 0);
}

// W fragment slot (slot<4096): dt=slot>>9, ks=(slot>>6)&7, lane=slot&63.
// ks<4: (Bm-C)[d][f], f=ks*32+lr*8+j ; ks>=4: Dm[d][f]; d=dt*16+(lane&15).
__device__ __forceinline__ bf16x8 w_frag(const float* __restrict__ w1, int slot) {
  int lane = slot & 63, ks = (slot >> 6) & 7, dt = slot >> 9;
  int d = dt * 16 + (lane & 15), lr = lane >> 4;
  const float* r = w1 + (size_t)d * 512;
  bf16x8 v;
  if (ks < 4) {
    int f0 = ks * 32 + lr * 8;
    f32x4 b0 = *(const f32x4*)(r + 128 + f0), b1 = *(const f32x4*)(r + 132 + f0);
    f32x4 c0 = *(const f32x4*)(r + 256 + f0), c1 = *(const f32x4*)(r + 260 + f0);
    v[0]=f2bf(b0.x-c0.x); v[1]=f2bf(b0.y-c0.y); v[2]=f2bf(b0.z-c0.z); v[3]=f2bf(b0.w-c0.w);
    v[4]=f2bf(b1.x-c1.x); v[5]=f2bf(b1.y-c1.y); v[6]=f2bf(b1.z-c1.z); v[7]=f2bf(b1.w-c1.w);
  } else {
    int f0 = (ks - 4) * 32 + lr * 8;
    f32x4 d0 = *(const f32x4*)(r + 384 + f0), d1 = *(const f32x4*)(r + 388 + f0);
    v[0]=f2bf(d0.x); v[1]=f2bf(d0.y); v[2]=f2bf(d0.z); v[3]=f2bf(d0.w);
    v[4]=f2bf(d1.x); v[5]=f2bf(d1.y); v[6]=f2bf(d1.z); v[7]=f2bf(d1.w);
  }
  return v;
}

__global__ void preW_kernel(const float* __restrict__ w1, unsigned short* __restrict__ Wp,
                            float* __restrict__ sTd, float* __restrict__ sTf) {
  int idx = blockIdx.x * 256 + threadIdx.x;  // 64*256 = 16384
  int d = idx >> 7, f = idx & 127;
  float s = w1[(size_t)d * 512 + f] + w1[(size_t)d * 512 + 256 + f];  // (A+C)
  sTd[idx] = s;                       // d-major (din fallback)
  sTf[(size_t)f * 128 + d] = s;       // f-major (preU, coalesced)
  if (idx < 4096) *(bf16x8*)(Wp + (size_t)idx * 8) = w_frag(w1, idx);
}

__global__ void preU_kernel(const float* __restrict__ qg, const float* __restrict__ sTf,
                            const float* __restrict__ b1g, float* __restrict__ uall) {
  __shared__ float qs[128];
  int b = blockIdx.x, d = threadIdx.x;
  qs[d] = qg[(size_t)b * 128 + d];
  __syncthreads();
  float acc = b1g[d];
  #pragma unroll 16
  for (int f = 0; f < 128; ++f) acc += qs[f] * sTf[(size_t)f * 128 + d];
  uall[(size_t)b * 128 + d] = acc;
}

__device__ __forceinline__ bool mask_at(const void* m, int mcode, size_t i) {
  if (mcode == 0) return ((const int*)m)[i] != 0;
  if (mcode == 1) return ((const unsigned char*)m)[i] != 0;
  return ((const float*)m)[i] != 0.f;
}

// LDS bytes: [0,65536) W; [65536,67584) u[4][128] f32; [67584,68096) w2[128];
// [68096,69120) qbf[4][128]bf16; [69120,73216) outl[8][128] f32; [73216,73280) red[16]
__global__ __launch_bounds__(512, 2) void din_kernel(
    const float* __restrict__ qg, const float* __restrict__ keysg,
    const void* __restrict__ maskg, const float* __restrict__ w1g,
    const float* __restrict__ b1g, const float* __restrict__ pag,
    const float* __restrict__ w2g, const float* __restrict__ b2g,
    const unsigned short* __restrict__ Wp, const float* __restrict__ sTd,
    const float* __restrict__ uall, int mode, float* __restrict__ outg) {
  __shared__ __align__(16) char smem[73280];
  unsigned short* Wlds = (unsigned short*)smem;
  float* u_lds = (float*)(smem + 65536);
  float* w2l   = (float*)(smem + 67584);
  char*  qbfb  = smem + 68096;
  float* outl  = (float*)(smem + 69120);
  float* red   = (float*)(smem + 73216);

  const int tid  = threadIdx.x;
  const int wid  = tid >> 6;               // 0..7
  const int lane = tid & 63;
  const int lrow = lane >> 4;              // 0..3
  const int lcol = lane & 15;
  const int half = wid & 1;                // t-half of this wave
  const int bl   = wid >> 1;               // block-local b (0..3)
  const int b    = __builtin_amdgcn_readfirstlane((blockIdx.x << 2) + bl);

  const float* qb    = qg + (size_t)b * 128;
  const float* keysB = keysg + (size_t)b * T * 128;

  // ---- mask dtype detector (wave-uniform) ----
  int mcode;
  {
    unsigned v = ((const unsigned*)maskg)[lane];
    unsigned c0 = v & 255u, c1 = (v >> 8) & 255u, c2 = (v >> 16) & 255u, c3 = v >> 24;
    bool weird = (c0 == 0x80u) | (c0 == 0x3Fu) | (c1 == 0x80u) | (c1 == 0x3Fu) |
                 (c2 == 0x80u) | (c2 == 0x3Fu) | (c3 == 0x80u) | (c3 == 0x3Fu);
    bool nz = (v & 0xFFFFFF00u) != 0u;
    unsigned long long bw = __ballot(weird);
    unsigned long long bn = __ballot(nz);
    mcode = bw ? 2 : (bn ? 1 : 0);  // 2=f32, 1=byte, 0=int32
  }

  const float pa  = pag[0];
  const float b2v = b2g[0];

  const int t0 = half * 7;                 // tiles [t0, t1)
  const int t1 = half ? 13 : 7;

  // ---- K tile prefetch halves (A-frag: row=lcol, f=ks*32+lrow*8+j) ----
  f32x4 kf0[4], kf1[4];
  #define LOADK_H(TILE, KA, KB)                                    \
    do {                                                           \
      int trow_ = (TILE) * 16 + lcol;                              \
      int trc_ = trow_ < T ? trow_ : T - 1;                        \
      const float* kr_ = keysB + (size_t)trc_ * 128 + lrow * 8;    \
      kf0[KA] = *(const f32x4*)(kr_ + (KA) * 32);                  \
      kf1[KA] = *(const f32x4*)(kr_ + (KA) * 32 + 4);              \
      kf0[KB] = *(const f32x4*)(kr_ + (KB) * 32);                  \
      kf1[KB] = *(const f32x4*)(kr_ + (KB) * 32 + 4);              \
    } while (0)
  LOADK_H(t0, 0, 1);
  LOADK_H(t0, 2, 3);

  // ---- stage W: 64 KB, linear, conflict-free ----
  if (mode) {
    #pragma unroll
    for (int i = 0; i < 8; ++i)
      async_cp16((const char*)Wp + ((size_t)tid + i * 512) * 16,
                 (char*)Wlds + ((size_t)tid + i * 512) * 16);
  } else {
    #pragma unroll
    for (int i = 0; i < 8; ++i) {
      int slot = tid + i * 512;
      *(bf16x8*)((char*)Wlds + (size_t)slot * 16) = w_frag(w1g, slot);
    }
  }

  // ---- u[bl][d] -> LDS ----
  if (mode == 2) {
    u_lds[tid & 511] = uall[(size_t)((blockIdx.x << 2) + (tid >> 7)) * 128 + (tid & 127)];
  } else if (half == 0) {
    f32x4 qq[8];
    #pragma unroll
    for (int i = 0; i < 8; ++i) qq[i] = *(const f32x4*)(qb + lrow * 32 + i * 4);
    #pragma unroll
    for (int dt = 0; dt < 8; ++dt) {
      int d = dt * 16 + lcol;
      float acc = 0.f;
      if (mode == 1) {
        const float* sp = sTd + (size_t)d * 128 + lrow * 32;
        #pragma unroll
        for (int i = 0; i < 8; ++i) {
          f32x4 sv = *(const f32x4*)(sp + i * 4);
          acc += qq[i].x*sv.x + qq[i].y*sv.y + qq[i].z*sv.z + qq[i].w*sv.w;
        }
      } else {
        const float* r = w1g + (size_t)d * 512 + lrow * 32;
        #pragma unroll
        for (int i = 0; i < 8; ++i) {
          f32x4 av = *(const f32x4*)(r + i * 4);
          f32x4 cv = *(const f32x4*)(r + 256 + i * 4);
          acc += qq[i].x*(av.x+cv.x) + qq[i].y*(av.y+cv.y) +
                 qq[i].z*(av.z+cv.z) + qq[i].w*(av.w+cv.w);
        }
      }
      acc += __shfl_xor(acc, 16);
      acc += __shfl_xor(acc, 32);
      if (lrow == 0) u_lds[bl * 128 + d] = acc + b1g[d];
    }
  }

  // ---- w2 -> LDS; q (bf16) -> LDS (one wave per b) ----
  if (tid < 128) w2l[tid] = w2g[tid];
  if (half == 0 && lane < 16) {
    f32x4 qa = *(const f32x4*)(qb + lane * 8);
    f32x4 qc = *(const f32x4*)(qb + lane * 8 + 4);
    bf16x8 qv;
    qv[0]=f2bf(qa.x); qv[1]=f2bf(qa.y); qv[2]=f2bf(qa.z); qv[3]=f2bf(qa.w);
    qv[4]=f2bf(qc.x); qv[5]=f2bf(qc.y); qv[6]=f2bf(qc.z); qv[7]=f2bf(qc.w);
    *(bf16x8*)(qbfb + bl * 256 + lane * 16) = qv;
  }

  // ---- mask -> 2 wave-uniform u64 bitmasks for this half's t-range ----
  unsigned long long mw0, mw1;
  {
    size_t base = (size_t)b * T + half * 112;
    bool v0 = mask_at(maskg, mcode, base + lane);                       // rel 0..63
    bool v1 = half ? ((64 + lane < 88) ? mask_at(maskg, mcode, base + 64 + lane) : false)
                   : mask_at(maskg, mcode, base + 64 + lane);           // rel 64..
    mw0 = __ballot(v0); mw1 = __ballot(v1);
  }

  __syncthreads();  // THE barrier: W/u/w2/q staged; waves free-run after

  float m_w = -1e9f, den_w = 0.f;
  float accpv[32];
  #pragma unroll
  for (int i = 0; i < 32; ++i) accpv[i] = 0.f;

  #define WF(DT, KS) (*(const bf16x8*)((const char*)Wlds + (((DT)*8+(KS))*64+lane)*16))

  #define MFMA_DTP(DT0, DT1)                                                   \
    {                                                                          \
      float u0 = u_lds[bl * 128 + (DT0) * 16 + lcol];                          \
      float u1 = u_lds[bl * 128 + (DT1) * 16 + lcol];                          \
      f32x4 acc0 = {u0, u0, u0, u0}, acc1 = {u1, u1, u1, u1};                  \
      _Pragma("unroll")                                                        \
      for (int ks = 0; ks < 4; ++ks) {                                         \
        acc0 = __builtin_amdgcn_mfma_f32_16x16x32_bf16(af[ks], WF(DT0, ks), acc0, 0, 0, 0); \
        acc1 = __builtin_amdgcn_mfma_f32_16x16x32_bf16(af[ks], WF(DT1, ks), acc1, 0, 0, 0); \
      }                                                                        \
      _Pragma("unroll")                                                        \
      for (int ks = 0; ks < 4; ++ks) {                                         \
        acc0 = __builtin_amdgcn_mfma_f32_16x16x32_bf16(afq[ks], WF(DT0, 4 + ks), acc0, 0, 0, 0); \
        acc1 = __builtin_amdgcn_mfma_f32_16x16x32_bf16(afq[ks], WF(DT1, 4 + ks), acc1, 0, 0, 0); \
      }                                                                        \
      float w20 = w2l[(DT0) * 16 + lcol], w21 = w2l[(DT1) * 16 + lcol];        \
      _Pragma("unroll")                                                        \
      for (int j = 0; j < 4; ++j) {                                            \
        float h0 = acc0[j]; h0 = (h0 >= 0.f) ? h0 : pa * h0;                   \
        float h1 = acc1[j]; h1 = (h1 >= 0.f) ? h1 : pa * h1;                   \
        sj[j] += h0 * w20 + h1 * w21;                                          \
      }                                                                        \
    }

  for (int tile = t0; tile < t1; ++tile) {
    // cvt kf -> af (k) + afq (q*k, q from LDS); kf freed at this point
    bf16x8 af[4], afq[4];
    #pragma unroll
    for (int ks = 0; ks < 4; ++ks) {
      bf16x8 qp = *(const bf16x8*)(qbfb + bl * 256 + ks * 64 + lrow * 16);
      af[ks][0]=f2bf(kf0[ks].x); af[ks][1]=f2bf(kf0[ks].y);
      af[ks][2]=f2bf(kf0[ks].z); af[ks][3]=f2bf(kf0[ks].w);
      af[ks][4]=f2bf(kf1[ks].x); af[ks][5]=f2bf(kf1[ks].y);
      af[ks][6]=f2bf(kf1[ks].z); af[ks][7]=f2bf(kf1[ks].w);
      afq[ks][0]=f2bf(kf0[ks].x*bf2f(qp[0])); afq[ks][1]=f2bf(kf0[ks].y*bf2f(qp[1]));
      afq[ks][2]=f2bf(kf0[ks].z*bf2f(qp[2])); afq[ks][3]=f2bf(kf0[ks].w*bf2f(qp[3]));
      afq[ks][4]=f2bf(kf1[ks].x*bf2f(qp[4])); afq[ks][5]=f2bf(kf1[ks].y*bf2f(qp[5]));
      afq[ks][6]=f2bf(kf1[ks].z*bf2f(qp[6])); afq[ks][7]=f2bf(kf1[ks].w*bf2f(qp[7]));
    }
    if (tile + 1 < t1) LOADK_H(tile + 1, 0, 1);  // prefetch half A (16 regs in flight)

    float sj[4] = {0.f, 0.f, 0.f, 0.f};
    MFMA_DTP(0, 1) MFMA_DTP(2, 3)
    if (tile + 1 < t1) LOADK_H(tile + 1, 2, 3);  // prefetch half B
    MFMA_DTP(4, 5) MFMA_DTP(6, 7)

    #pragma unroll
    for (int j = 0; j < 4; ++j) sj[j] = sum16(sj[j]);

    int relbase = tile * 16 - half * 112;   // 0,16,..,96 within the half
    unsigned long long mword = (relbase & 64) ? mw1 : mw0;
    float mt = -1e30f;
    #pragma unroll
    for (int j = 0; j < 4; ++j) {
      int bitp = (relbase & 63) + lrow * 4 + j;
      bool valid = (mword >> bitp) & 1ull;
      sj[j] = valid ? (sj[j] + b2v) : -1e30f;
      mt = fmaxf(mt, sj[j]);
    }
    mt = fmaxf(mt, __shfl_xor(mt, 16));
    mt = fmaxf(mt, __shfl_xor(mt, 32));

    if (mt > m_w) {  // exact defer-max
      float sc = __expf(m_w - mt);
      den_w *= sc;
      #pragma unroll
      for (int i = 0; i < 32; ++i) accpv[i] *= sc;
      m_w = mt;
    }
    float wj[4], dsum = 0.f;
    #pragma unroll
    for (int j = 0; j < 4; ++j) { wj[j] = __expf(sj[j] - m_w); dsum += wj[j]; }
    dsum += __shfl_xor(dsum, 16);
    dsum += __shfl_xor(dsum, 32);
    den_w += dsum;

    // broadcast weight for this lane's K row (t = tile*16 + lcol)
    float tmp = (lcol & 2) ? ((lcol & 1) ? wj[3] : wj[2])
                           : ((lcol & 1) ? wj[1] : wj[0]);
    float wtr = __shfl(tmp, ((lcol >> 2) << 4) | (lcol & 3), 64);

    // PV from bf16 af (unpack + FMA)
    #pragma unroll
    for (int ks = 0; ks < 4; ++ks) {
      #pragma unroll
      for (int i = 0; i < 8; ++i)
        accpv[ks * 8 + i] += wtr * bf2f(af[ks][i]);
    }
  }

  // ---- fold K-rows via DPP; write per-wave partials; merge wave-pairs ----
  #pragma unroll
  for (int i = 0; i < 32; ++i) accpv[i] = sum16(accpv[i]);
  if (lcol == 0) {
    #pragma unroll
    for (int ks = 0; ks < 4; ++ks) {
      f32x4 a = {accpv[ks*8+0], accpv[ks*8+1], accpv[ks*8+2], accpv[ks*8+3]};
      f32x4 c = {accpv[ks*8+4], accpv[ks*8+5], accpv[ks*8+6], accpv[ks*8+7]};
      *(f32x4*)(outl + wid * 128 + ks * 32 + lrow * 8)     = a;
      *(f32x4*)(outl + wid * 128 + ks * 32 + lrow * 8 + 4) = c;
    }
  }
  if (lane == 0) { red[wid] = m_w; red[8 + wid] = den_w; }

  __syncthreads();  // partials ready

  {
    int obl = tid >> 7, d = tid & 127;
    int w0 = obl * 2, w1i = w0 + 1;
    float M = fmaxf(red[w0], red[w1i]);
    float e0 = __expf(red[w0] - M), e1 = __expf(red[w1i] - M);
    float den = red[8 + w0] * e0 + red[8 + w1i] * e1;
    float o   = outl[w0 * 128 + d] * e0 + outl[w1i * 128 + d] * e1;
    float inv = (den > 0.f) ? 1.0f / den : 0.f;
    outg[(size_t)((blockIdx.x << 2) + obl) * 128 + d] = o * inv;
  }
  #undef MFMA_DTP
  #undef WF
  #undef LOADK_H
}

}  // namespace

extern "C" void kernel_launch(void* const* d_in, const int* in_sizes, int n_in,
                              void* d_out, int out_size, void* d_ws, size_t ws_size,
                              hipStream_t stream) {
  (void)in_sizes; (void)n_in; (void)out_size;
  const float* q    = (const float*)d_in[0];
  const float* keys = (const float*)d_in[1];
  const void*  mask = d_in[2];
  const float* w1   = (const float*)d_in[3];
  const float* b1   = (const float*)d_in[4];
  const float* pa   = (const float*)d_in[5];
  const float* w2   = (const float*)d_in[6];
  const float* b2   = (const float*)d_in[7];
  float* out = (float*)d_out;

  unsigned short* Wp = (unsigned short*)d_ws;      // 64 KB bf16 frag table
  float* sTd  = (float*)((char*)d_ws + 65536);     // 64 KB (A+C) d-major
  float* sTf  = (float*)((char*)d_ws + 131072);    // 64 KB (A+C) f-major
  float* uall = (float*)((char*)d_ws + 196608);    // 1 MB u[B][128]
  int mode = 0;
  if (ws_size >= (size_t)196608 + (size_t)2048 * 128 * 4) mode = 2;
  else if (ws_size >= (size_t)131072)                     mode = 1;

  if (mode >= 1) preW_kernel<<<64, 256, 0, stream>>>(w1, Wp, sTd, sTf);
  if (mode == 2) preU_kernel<<<2048, 128, 0, stream>>>(q, sTf, b1, uall);
  din_kernel<<<512, 512, 0, stream>>>(q, keys, mask, w1, b1, pa, w2, b2,
                                      Wp, sTd, uall, mode, out);
}

// Round 10
// 90.686 us; speedup vs baseline: 4.1103x; 4.1103x over previous
//
#include <hip/hip_runtime.h>
#include <hip/hip_bf16.h>

namespace {

constexpr int T = 200;

typedef float f32x4 __attribute__((ext_vector_type(4)));
typedef short bf16x8 __attribute__((ext_vector_type(8)));
typedef unsigned int u32;
typedef u32 u32x4 __attribute__((ext_vector_type(4)));

__device__ __forceinline__ short f2bf(float f) {
  __hip_bfloat16 h = __float2bfloat16(f);  // RNE; pairs fuse to v_cvt_pk_bf16_f32
  return __builtin_bit_cast(short, h);
}
__device__ __forceinline__ float bf2f(short s) {
  return __uint_as_float(((unsigned)(unsigned short)s) << 16);
}
__device__ __forceinline__ float bflo2f(u32 u) { return __uint_as_float(u << 16); }
__device__ __forceinline__ float bfhi2f(u32 u) { return __uint_as_float(u & 0xFFFF0000u); }

template <int CTRL>
__device__ __forceinline__ float dpp_add(float x) {
  int y = __builtin_amdgcn_update_dpp(0, __float_as_int(x), CTRL, 0xF, 0xF, true);
  return x + __int_as_float(y);
}
__device__ __forceinline__ float sum16(float x) {
  x = dpp_add<0x121>(x); x = dpp_add<0x122>(x);   // row_ror 1,2,4,8
  x = dpp_add<0x124>(x); x = dpp_add<0x128>(x);
  return x;
}

__device__ __forceinline__ void async_cp16(const void* g, void* l) {
  __builtin_amdgcn_global_load_lds((__attribute__((address_space(1))) void*)g,
                                   (__attribute__((address_space(3))) void*)l, 16, 0, 0);
}

__device__ __forceinline__ bool mask_at(const void* m, int mcode, size_t i) {
  if (mcode == 0) return ((const int*)m)[i] != 0;
  if (mcode == 1) return ((const unsigned char*)m)[i] != 0;
  return ((const float*)m)[i] != 0.f;
}

// Frag-slot decode (slot<2048): lane=s&63, ks=(s>>6)&3, dt=s>>8;
// element j in [0,8): d=dt*16+(lane&15), f=ks*32+(lane>>4)*8+j.
// M[d][f] = (Bm-C)[d][f] + Dm[d][f]*q[f];  frag = MFMA B-operand layout.

// preW: MDfrag[16384] u32 (lo=Bm-C, hi=Dm, frag-elem order) + sTf[16384] f-major (A+C)
__global__ void preW_kernel(const float* __restrict__ w1, u32* __restrict__ MDfrag,
                            float* __restrict__ sTf) {
  int idx = blockIdx.x * 256 + threadIdx.x;  // 64*256 = 16384
  {
    int d = idx >> 7, f = idx & 127;
    sTf[(size_t)f * 128 + d] = w1[(size_t)d * 512 + f] + w1[(size_t)d * 512 + 256 + f];
  }
  int s = idx >> 3, j = idx & 7;
  int lane = s & 63, ks = (s >> 6) & 3, dt = s >> 8;
  int d = dt * 16 + (lane & 15), f = ks * 32 + (lane >> 4) * 8 + j;
  const float* r = w1 + (size_t)d * 512;
  u32 lo = (unsigned short)f2bf(r[128 + f] - r[256 + f]);
  u32 hi = (unsigned short)f2bf(r[384 + f]);
  MDfrag[idx] = lo | (hi << 16);
}

// preU: uall[b][d] = b1[d] + sum_f q[b][f]*(A+C)[d][f]
__global__ void preU_kernel(const float* __restrict__ qg, const float* __restrict__ sTf,
                            const float* __restrict__ b1g, float* __restrict__ uall) {
  __shared__ float qs[128];
  int b = blockIdx.x, d = threadIdx.x;
  qs[d] = qg[(size_t)b * 128 + d];
  __syncthreads();
  float acc = b1g[d];
  #pragma unroll 16
  for (int f = 0; f < 128; ++f) acc += qs[f] * sTf[(size_t)f * 128 + d];
  uall[(size_t)b * 128 + d] = acc;
}

// preM: Mall[b] = per-b bf16 frag table (32 KB each)
__global__ void preM_kernel(const u32* __restrict__ MDfrag, const float* __restrict__ qg,
                            unsigned short* __restrict__ Mall) {
  __shared__ float qs[128];
  int b = blockIdx.x, tid = threadIdx.x;
  if (tid < 128) qs[tid] = qg[(size_t)b * 128 + tid];
  __syncthreads();
  unsigned short* mb = Mall + (size_t)b * 16384;
  #pragma unroll
  for (int i = 0; i < 8; ++i) {
    int s = tid + i * 256;
    int lane = s & 63, ks = (s >> 6) & 3;
    int f0 = ks * 32 + (lane >> 4) * 8;
    u32x4 A = *(const u32x4*)(MDfrag + (size_t)s * 8);
    u32x4 B = *(const u32x4*)(MDfrag + (size_t)s * 8 + 4);
    f32x4 q0 = *(const f32x4*)(qs + f0), q1 = *(const f32x4*)(qs + f0 + 4);
    bf16x8 v;
    v[0] = f2bf(bflo2f(A.x) + bfhi2f(A.x) * q0.x);
    v[1] = f2bf(bflo2f(A.y) + bfhi2f(A.y) * q0.y);
    v[2] = f2bf(bflo2f(A.z) + bfhi2f(A.z) * q0.z);
    v[3] = f2bf(bflo2f(A.w) + bfhi2f(A.w) * q0.w);
    v[4] = f2bf(bflo2f(B.x) + bfhi2f(B.x) * q1.x);
    v[5] = f2bf(bflo2f(B.y) + bfhi2f(B.y) * q1.y);
    v[6] = f2bf(bflo2f(B.z) + bfhi2f(B.z) * q1.z);
    v[7] = f2bf(bflo2f(B.w) + bfhi2f(B.w) * q1.w);
    *(bf16x8*)(mb + (size_t)s * 8) = v;
  }
}

// LDS: Mg[2][32768] @0 ; ug[2][128]f32 @65536 ; w2l[128] @66560 ;
// outl[2][4][128]f32 @67072 ; red[2][16] @71168 ; qs[2][128] @71296 ; total 72320
__global__ __launch_bounds__(512, 2) void din_kernel(
    const float* __restrict__ qg, const float* __restrict__ keysg,
    const void* __restrict__ maskg, const float* __restrict__ w1g,
    const float* __restrict__ b1g, const float* __restrict__ pag,
    const float* __restrict__ w2g, const float* __restrict__ b2g,
    const u32* __restrict__ MDfrag, const unsigned short* __restrict__ Mall,
    const float* __restrict__ uall, int hasPre, int hasU, int hasM,
    float* __restrict__ outg) {
  __shared__ __align__(16) char smem[72320];

  const int tid  = threadIdx.x;
  const int wid  = tid >> 6;               // 0..7
  const int lane = tid & 63;
  const int lrow = lane >> 4;              // 0..3
  const int lcol = lane & 15;
  const int g    = wid >> 2;               // group 0/1
  const int wg   = wid & 3;                // wave in group
  const int tidg = tid & 255;
  const int b    = __builtin_amdgcn_readfirstlane((blockIdx.x << 1) + g);

  char*  Mg   = smem + g * 32768;
  float* ug   = (float*)(smem + 65536) + g * 128;
  float* w2l  = (float*)(smem + 66560);
  float* outl = (float*)(smem + 67072) + g * 512;
  float* redg = (float*)(smem + 71168) + g * 16;
  float* qsg  = (float*)(smem + 71296) + g * 128;

  const float* qb    = qg + (size_t)b * 128;
  const float* keysB = keysg + (size_t)b * T * 128;

  // ---- mask dtype detector (wave-uniform) ----
  int mcode;
  {
    unsigned v = ((const unsigned*)maskg)[lane];
    unsigned c0 = v & 255u, c1 = (v >> 8) & 255u, c2 = (v >> 16) & 255u, c3 = v >> 24;
    bool weird = (c0 == 0x80u) | (c0 == 0x3Fu) | (c1 == 0x80u) | (c1 == 0x3Fu) |
                 (c2 == 0x80u) | (c2 == 0x3Fu) | (c3 == 0x80u) | (c3 == 0x3Fu);
    bool nz = (v & 0xFFFFFF00u) != 0u;
    unsigned long long bw = __ballot(weird);
    unsigned long long bn = __ballot(nz);
    mcode = bw ? 2 : (bn ? 1 : 0);  // 2=f32, 1=byte, 0=int32
  }

  const float pa  = pag[0];
  const float b2v = b2g[0];

  // ---- first K tile prefetch (A-frag: row=lcol, f=ks*32+lrow*8+j) ----
  f32x4 kf0[4], kf1[4];
  #define LOADK(TILE)                                              \
    do {                                                           \
      int trow_ = (TILE) * 16 + lcol;                              \
      int trc_ = trow_ < T ? trow_ : T - 1;                        \
      const float* kr_ = keysB + (size_t)trc_ * 128 + lrow * 8;    \
      _Pragma("unroll")                                            \
      for (int ks = 0; ks < 4; ++ks) {                             \
        kf0[ks] = *(const f32x4*)(kr_ + ks * 32);                  \
        kf1[ks] = *(const f32x4*)(kr_ + ks * 32 + 4);              \
      }                                                            \
    } while (0)
  LOADK(wg);

  // ---- stage M (32 KB per group) ----
  if (hasM) {
    #pragma unroll
    for (int i = 0; i < 8; ++i)
      async_cp16((const char*)Mall + (size_t)b * 32768 + ((size_t)tidg + i * 256) * 16,
                 Mg + ((size_t)tidg + i * 256) * 16);
  } else {
    if (tidg < 128) qsg[tidg] = qb[tidg];
    __syncthreads();
    #pragma unroll
    for (int i = 0; i < 8; ++i) {
      int s = tidg + i * 256;
      int lane_ = s & 63, ks = (s >> 6) & 3;
      int f0 = ks * 32 + (lane_ >> 4) * 8;
      bf16x8 v;
      if (hasPre) {
        u32x4 A = *(const u32x4*)(MDfrag + (size_t)s * 8);
        u32x4 B = *(const u32x4*)(MDfrag + (size_t)s * 8 + 4);
        f32x4 q0 = *(const f32x4*)(qsg + f0), q1 = *(const f32x4*)(qsg + f0 + 4);
        v[0] = f2bf(bflo2f(A.x) + bfhi2f(A.x) * q0.x);
        v[1] = f2bf(bflo2f(A.y) + bfhi2f(A.y) * q0.y);
        v[2] = f2bf(bflo2f(A.z) + bfhi2f(A.z) * q0.z);
        v[3] = f2bf(bflo2f(A.w) + bfhi2f(A.w) * q0.w);
        v[4] = f2bf(bflo2f(B.x) + bfhi2f(B.x) * q1.x);
        v[5] = f2bf(bflo2f(B.y) + bfhi2f(B.y) * q1.y);
        v[6] = f2bf(bflo2f(B.z) + bfhi2f(B.z) * q1.z);
        v[7] = f2bf(bflo2f(B.w) + bfhi2f(B.w) * q1.w);
      } else {
        int dt = s >> 8, d = dt * 16 + (lane_ & 15);
        const float* r = w1g + (size_t)d * 512;
        #pragma unroll
        for (int j = 0; j < 8; ++j) {
          int f = f0 + j;
          v[j] = f2bf((r[128 + f] - r[256 + f]) + r[384 + f] * qsg[f]);
        }
      }
      *(bf16x8*)(Mg + (size_t)s * 16) = v;
    }
  }

  // ---- u ----
  if (hasU) {
    if (tidg < 128) ug[tidg] = uall[(size_t)b * 128 + tidg];
  } else {
    // emergency: each wave computes 2 dt's from w1 (q in qsg, staged above)
    #pragma unroll
    for (int k = 0; k < 2; ++k) {
      int dt = wg * 2 + k, d = dt * 16 + lcol;
      const float* r = w1g + (size_t)d * 512 + lrow * 32;
      float acc = 0.f;
      #pragma unroll
      for (int i = 0; i < 8; ++i) {
        f32x4 qv = *(const f32x4*)(qsg + lrow * 32 + i * 4);
        f32x4 av = *(const f32x4*)(r + i * 4);
        f32x4 cv = *(const f32x4*)(r + 256 + i * 4);
        acc += qv.x*(av.x+cv.x) + qv.y*(av.y+cv.y) + qv.z*(av.z+cv.z) + qv.w*(av.w+cv.w);
      }
      acc += __shfl_xor(acc, 16);
      acc += __shfl_xor(acc, 32);
      if (lrow == 0) ug[d] = acc + b1g[d];
    }
  }

  if (tid < 128) w2l[tid] = w2g[tid];

  // ---- mask -> 4 wave-uniform u64 bitmasks ----
  unsigned long long mw0, mw1, mw2, mw3;
  {
    size_t base = (size_t)b * T;
    bool v0 = mask_at(maskg, mcode, base + lane);
    bool v1 = mask_at(maskg, mcode, base + 64 + lane);
    bool v2 = mask_at(maskg, mcode, base + 128 + lane);
    bool v3 = (192 + lane < T) ? mask_at(maskg, mcode, base + 192 + lane) : false;
    mw0 = __ballot(v0); mw1 = __ballot(v1); mw2 = __ballot(v2); mw3 = __ballot(v3);
  }

  __syncthreads();  // M/u/w2 staged (drains async loads); waves free-run after

  float m_w = -1e9f, den_w = 0.f;
  float accpv[32];
  #pragma unroll
  for (int i = 0; i < 32; ++i) accpv[i] = 0.f;

  #define MF(DT, KS) (*(const bf16x8*)(Mg + (((DT) * 4 + (KS)) * 64 + lane) * 16))

  #define BODY(TILE, PF)                                                        \
    do {                                                                        \
      const int tile_ = (TILE);                                                 \
      bf16x8 af[4];                                                             \
      _Pragma("unroll")                                                         \
      for (int ks = 0; ks < 4; ++ks) {                                          \
        af[ks][0]=f2bf(kf0[ks].x); af[ks][1]=f2bf(kf0[ks].y);                   \
        af[ks][2]=f2bf(kf0[ks].z); af[ks][3]=f2bf(kf0[ks].w);                   \
        af[ks][4]=f2bf(kf1[ks].x); af[ks][5]=f2bf(kf1[ks].y);                   \
        af[ks][6]=f2bf(kf1[ks].z); af[ks][7]=f2bf(kf1[ks].w);                   \
      }                                                                         \
      if ((PF) >= 0) LOADK(PF);                                                 \
      float sj[4] = {0.f, 0.f, 0.f, 0.f};                                       \
      _Pragma("unroll")                                                         \
      for (int dp = 0; dp < 4; ++dp) {                                          \
        int d0_ = dp * 2, d1_ = dp * 2 + 1;                                     \
        float u0 = ug[d0_ * 16 + lcol], u1 = ug[d1_ * 16 + lcol];               \
        f32x4 acc0 = {u0, u0, u0, u0}, acc1 = {u1, u1, u1, u1};                 \
        _Pragma("unroll")                                                       \
        for (int ks = 0; ks < 4; ++ks) {                                        \
          acc0 = __builtin_amdgcn_mfma_f32_16x16x32_bf16(af[ks], MF(d0_, ks), acc0, 0, 0, 0); \
          acc1 = __builtin_amdgcn_mfma_f32_16x16x32_bf16(af[ks], MF(d1_, ks), acc1, 0, 0, 0); \
        }                                                                       \
        float w20 = w2l[d0_ * 16 + lcol], w21 = w2l[d1_ * 16 + lcol];           \
        _Pragma("unroll")                                                       \
        for (int j = 0; j < 4; ++j) {                                           \
          float h0 = acc0[j]; h0 = (h0 >= 0.f) ? h0 : pa * h0;                  \
          float h1 = acc1[j]; h1 = (h1 >= 0.f) ? h1 : pa * h1;                  \
          sj[j] += h0 * w20 + h1 * w21;                                         \
        }                                                                       \
      }                                                                         \
      _Pragma("unroll")                                                         \
      for (int j = 0; j < 4; ++j) sj[j] = sum16(sj[j]);                         \
      unsigned long long mword = tile_ < 4 ? mw0 : tile_ < 8 ? mw1              \
                                 : tile_ < 12 ? mw2 : mw3;                      \
      float mt = -1e30f;                                                        \
      _Pragma("unroll")                                                         \
      for (int j = 0; j < 4; ++j) {                                             \
        int bitp = ((tile_ & 3) << 4) + lrow * 4 + j;                           \
        bool valid = (mword >> bitp) & 1ull;                                    \
        sj[j] = valid ? (sj[j] + b2v) : -1e30f;                                 \
        mt = fmaxf(mt, sj[j]);                                                  \
      }                                                                         \
      mt = fmaxf(mt, __shfl_xor(mt, 16));                                       \
      mt = fmaxf(mt, __shfl_xor(mt, 32));                                       \
      if (mt > m_w) {  /* exact defer-max */                                    \
        float sc = __expf(m_w - mt);                                            \
        den_w *= sc;                                                            \
        _Pragma("unroll")                                                       \
        for (int i = 0; i < 32; ++i) accpv[i] *= sc;                            \
        m_w = mt;                                                               \
      }                                                                         \
      float wj[4], dsum = 0.f;                                                  \
      _Pragma("unroll")                                                         \
      for (int j = 0; j < 4; ++j) { wj[j] = __expf(sj[j] - m_w); dsum += wj[j]; } \
      dsum += __shfl_xor(dsum, 16);                                             \
      dsum += __shfl_xor(dsum, 32);                                             \
      den_w += dsum;                                                            \
      float tmp = (lcol & 2) ? ((lcol & 1) ? wj[3] : wj[2])                     \
                             : ((lcol & 1) ? wj[1] : wj[0]);                    \
      float wtr = __shfl(tmp, ((lcol >> 2) << 4) | (lcol & 3), 64);             \
      _Pragma("unroll")                                                         \
      for (int ks = 0; ks < 4; ++ks) {                                          \
        _Pragma("unroll")                                                       \
        for (int i = 0; i < 8; ++i)                                             \
          accpv[ks * 8 + i] += wtr * bf2f(af[ks][i]);                           \
      }                                                                         \
    } while (0)

  // wave wg owns tiles wg, wg+4, wg+8 (+ tile 12 for wg==0)
  BODY(wg, wg + 4);
  BODY(wg + 4, wg + 8);
  BODY(wg + 8, (wg == 0) ? 12 : -1);
  if (wg == 0) BODY(12, -1);

  // ---- fold K-rows via DPP; per-wave partials -> LDS; merge per group ----
  #pragma unroll
  for (int i = 0; i < 32; ++i) accpv[i] = sum16(accpv[i]);
  if (lcol == 0) {
    #pragma unroll
    for (int ks = 0; ks < 4; ++ks) {
      f32x4 a = {accpv[ks*8+0], accpv[ks*8+1], accpv[ks*8+2], accpv[ks*8+3]};
      f32x4 c = {accpv[ks*8+4], accpv[ks*8+5], accpv[ks*8+6], accpv[ks*8+7]};
      *(f32x4*)(outl + wg * 128 + ks * 32 + lrow * 8)     = a;
      *(f32x4*)(outl + wg * 128 + ks * 32 + lrow * 8 + 4) = c;
    }
  }
  if (lane == 0) { redg[wg] = m_w; redg[4 + wg] = den_w; }

  __syncthreads();  // partials ready

  if (tid < 256) {
    int gg = tid >> 7, d = tid & 127;
    const float* rg = (float*)(smem + 71168) + gg * 16;
    const float* og = (float*)(smem + 67072) + gg * 512;
    float M = fmaxf(fmaxf(rg[0], rg[1]), fmaxf(rg[2], rg[3]));
    float den = 0.f, o = 0.f;
    #pragma unroll
    for (int w = 0; w < 4; ++w) {
      float e = __expf(rg[w] - M);
      den += rg[4 + w] * e;
      o   += og[w * 128 + d] * e;
    }
    float inv = (den > 0.f) ? 1.0f / den : 0.f;
    outg[(size_t)((blockIdx.x << 1) + gg) * 128 + d] = o * inv;
  }
  #undef BODY
  #undef MF
  #undef LOADK
}

}  // namespace

extern "C" void kernel_launch(void* const* d_in, const int* in_sizes, int n_in,
                              void* d_out, int out_size, void* d_ws, size_t ws_size,
                              hipStream_t stream) {
  (void)in_sizes; (void)n_in; (void)out_size;
  const float* q    = (const float*)d_in[0];
  const float* keys = (const float*)d_in[1];
  const void*  mask = d_in[2];
  const float* w1   = (const float*)d_in[3];
  const float* b1   = (const float*)d_in[4];
  const float* pa   = (const float*)d_in[5];
  const float* w2   = (const float*)d_in[6];
  const float* b2   = (const float*)d_in[7];
  float* out = (float*)d_out;

  // ws layout: MDfrag u32[16384] @0 (64K) ; sTf f32[16384] @64K (64K) ;
  //            uall f32[2048*128] @128K (1M) ; Mall bf16[2048*16384] @128K+1M (64M)
  u32* MDfrag = (u32*)d_ws;
  float* sTf  = (float*)((char*)d_ws + 65536);
  float* uall = (float*)((char*)d_ws + 131072);
  unsigned short* Mall = (unsigned short*)((char*)d_ws + 131072 + 1048576);

  size_t needPre = 131072;
  size_t needU   = needPre + 1048576;
  size_t needM   = needU + (size_t)2048 * 32768;
  int hasPre = ws_size >= needPre;
  int hasU   = ws_size >= needU;
  int hasM   = ws_size >= needM;

  if (hasPre) preW_kernel<<<64, 256, 0, stream>>>(w1, MDfrag, sTf);
  if (hasU)   preU_kernel<<<2048, 128, 0, stream>>>(q, sTf, b1, uall);
  if (hasM)   preM_kernel<<<2048, 256, 0, stream>>>(MDfrag, q, Mall);
  din_kernel<<<1024, 512, 0, stream>>>(q, keys, mask, w1, b1, pa, w2, b2,
                                       MDfrag, Mall, uall, hasPre, hasU, hasM, out);
}

// Round 11
// 75.433 us; speedup vs baseline: 4.9415x; 1.2022x over previous
//
#include <hip/hip_runtime.h>
#include <hip/hip_bf16.h>

namespace {

constexpr int T  = 200;
constexpr int NT = 13;

typedef float f32x4 __attribute__((ext_vector_type(4)));
typedef short bf16x8 __attribute__((ext_vector_type(8)));
typedef unsigned int u32;
typedef u32 u32x4 __attribute__((ext_vector_type(4)));

__device__ __forceinline__ short f2bf(float f) {
  __hip_bfloat16 h = __float2bfloat16(f);
  return __builtin_bit_cast(short, h);
}
__device__ __forceinline__ float bflo2f(u32 u) { return __uint_as_float(u << 16); }
__device__ __forceinline__ float bfhi2f(u32 u) { return __uint_as_float(u & 0xFFFF0000u); }

template <int CTRL>
__device__ __forceinline__ float dpp_add(float x) {
  int y = __builtin_amdgcn_update_dpp(0, __float_as_int(x), CTRL, 0xF, 0xF, true);
  return x + __int_as_float(y);
}
__device__ __forceinline__ float sum16(float x) {
  x = dpp_add<0x121>(x); x = dpp_add<0x122>(x);
  x = dpp_add<0x124>(x); x = dpp_add<0x128>(x);
  return x;
}

// LDS floats: M 8192 (32KB bf16 128x128, slot^= (d&15)); u2[2][128]; outl[4][128]; red[8]
constexpr int OFF_U2   = 8192;
constexpr int OFF_OUTL = 8448;
constexpr int OFF_RED  = 8960;
constexpr int SMEM_F   = 8968;

__global__ void pre_kernel(const float* __restrict__ w1, u32* __restrict__ MD,
                           float* __restrict__ sTf) {
  int idx = blockIdx.x * 256 + threadIdx.x;  // 64 x 256 = 16384
  int d = idx >> 7, f = idx & 127;
  const float* r = w1 + (size_t)d * 512;
  u32 lo = (unsigned short)f2bf(r[128 + f] - r[256 + f]);  // Bm - C
  u32 hi = (unsigned short)f2bf(r[384 + f]);               // Dm
  MD[idx] = lo | (hi << 16);
  sTf[(size_t)f * 128 + d] = r[f] + r[256 + f];            // (A+C)^T, f-major
}

__global__ void preU_kernel(const float* __restrict__ qg, const float* __restrict__ sTf,
                            const float* __restrict__ b1g, float* __restrict__ uall) {
  __shared__ float qs[128];
  int b = blockIdx.x, d = threadIdx.x;
  qs[d] = qg[(size_t)b * 128 + d];
  __syncthreads();
  float acc = b1g[d];
  #pragma unroll 16
  for (int f = 0; f < 128; ++f) acc += qs[f] * sTf[(size_t)f * 128 + d];
  uall[(size_t)b * 128 + d] = acc;
}

__device__ __forceinline__ bool mask_at(const void* m, int mcode, size_t i) {
  if (mcode == 0) return ((const int*)m)[i] != 0;
  if (mcode == 1) return ((const unsigned char*)m)[i] != 0;
  return ((const float*)m)[i] != 0.f;
}

__global__ __launch_bounds__(256, 2) void din_kernel(
    const float* __restrict__ qg, const float* __restrict__ keysg,
    const void* __restrict__ maskg, const float* __restrict__ w1g,
    const float* __restrict__ b1g, const float* __restrict__ pag,
    const float* __restrict__ w2g, const float* __restrict__ b2g,
    const u32* __restrict__ MD, const float* __restrict__ uall,
    int mode, float* __restrict__ outg) {
  __shared__ __align__(16) float smem[SMEM_F];
  float* u2   = smem + OFF_U2;
  float* outl = smem + OFF_OUTL;
  float* red  = smem + OFF_RED;

  const int tid  = threadIdx.x;
  const int b    = blockIdx.x;
  const int wid  = tid >> 6;         // 0..3
  const int lane = tid & 63;
  const int lrow = (lane >> 4) & 3;
  const int lcol = lane & 15;

  const float* qb    = qg + (size_t)b * 128;
  const float* keysB = keysg + (size_t)b * T * 128;

  // ---- mask dtype detector (wave-uniform, no barrier) ----
  int mcode;
  {
    unsigned v = ((const unsigned*)maskg)[lane];
    unsigned c0 = v & 255u, c1 = (v >> 8) & 255u, c2 = (v >> 16) & 255u, c3 = v >> 24;
    bool weird = (c0 == 0x80u) | (c0 == 0x3Fu) | (c1 == 0x80u) | (c1 == 0x3Fu) |
                 (c2 == 0x80u) | (c2 == 0x3Fu) | (c3 == 0x80u) | (c3 == 0x3Fu);
    bool nz = (v & 0xFFFFFF00u) != 0u;
    unsigned long long bw = __ballot(weird);
    unsigned long long bn = __ballot(nz);
    mcode = bw ? 2 : (bn ? 1 : 0);  // 2=f32, 1=byte, 0=int32
  }

  const float pa  = pag[0];
  const float b2v = b2g[0];

  // ---- K-tile load into fp32 regs (A-frag: lane row=lcol, f=ks*32+lrow*8+j) ----
  f32x4 ka0[4], ka1[4], kb0[4], kb1[4];
  #define LOADK(K0, K1, TILE)                                        \
    do {                                                             \
      int trow_ = (TILE) * 16 + lcol;                                \
      int trc_  = trow_ < T ? trow_ : T - 1;                         \
      const float* kr_ = keysB + (size_t)trc_ * 128 + lrow * 8;      \
      _Pragma("unroll")                                              \
      for (int ks = 0; ks < 4; ++ks) {                               \
        K0[ks] = *(const f32x4*)(kr_ + ks * 32);                     \
        K1[ks] = *(const f32x4*)(kr_ + ks * 32 + 4);                 \
      }                                                              \
    } while (0)

  LOADK(ka0, ka1, wid);      // tiles wid and wid+4 prefetched through prologue
  LOADK(kb0, kb1, wid + 4);

  // ---- mask -> 4 wave-uniform u64 bitmasks (latency overlaps M build) ----
  unsigned long long mw0, mw1, mw2, mw3;
  {
    size_t base = (size_t)b * T;
    bool v0 = mask_at(maskg, mcode, base + lane);
    bool v1 = mask_at(maskg, mcode, base + 64 + lane);
    bool v2 = mask_at(maskg, mcode, base + 128 + lane);
    bool v3 = (192 + lane < T) ? mask_at(maskg, mcode, base + 192 + lane) : false;
    mw0 = __ballot(v0); mw1 = __ballot(v1); mw2 = __ballot(v2); mw3 = __ballot(v3);
  }

  // ---- build M in LDS: M[d][f] = (Bm-C)[d][f] + Dm[d][f]*q[f], bf16, swizzled ----
  if (mode >= 1) {
    #pragma unroll
    for (int i = 0; i < 8; ++i) {
      int e = i * 2048 + tid * 8;
      int d = e >> 7, f = e & 127;
      u32x4 A = *(const u32x4*)(MD + e);
      u32x4 B = *(const u32x4*)(MD + e + 4);
      f32x4 q0 = *(const f32x4*)(qb + f), q1 = *(const f32x4*)(qb + f + 4);
      bf16x8 v;
      v[0] = f2bf(bflo2f(A.x) + bfhi2f(A.x) * q0.x);
      v[1] = f2bf(bflo2f(A.y) + bfhi2f(A.y) * q0.y);
      v[2] = f2bf(bflo2f(A.z) + bfhi2f(A.z) * q0.z);
      v[3] = f2bf(bflo2f(A.w) + bfhi2f(A.w) * q0.w);
      v[4] = f2bf(bflo2f(B.x) + bfhi2f(B.x) * q1.x);
      v[5] = f2bf(bflo2f(B.y) + bfhi2f(B.y) * q1.y);
      v[6] = f2bf(bflo2f(B.z) + bfhi2f(B.z) * q1.z);
      v[7] = f2bf(bflo2f(B.w) + bfhi2f(B.w) * q1.w);
      int slot = (f >> 3) ^ (d & 15);
      *(bf16x8*)((char*)smem + d * 256 + slot * 16) = v;
    }
  } else {
    #pragma unroll
    for (int i = 0; i < 8; ++i) {
      int e = i * 2048 + tid * 8;
      int d = e >> 7, f = e & 127;
      const float* r = w1g + (size_t)d * 512;
      f32x4 bB0 = *(const f32x4*)(r + 128 + f), bB1 = *(const f32x4*)(r + 128 + f + 4);
      f32x4 cC0 = *(const f32x4*)(r + 256 + f), cC1 = *(const f32x4*)(r + 256 + f + 4);
      f32x4 dd0 = *(const f32x4*)(r + 384 + f), dd1 = *(const f32x4*)(r + 384 + f + 4);
      f32x4 q0 = *(const f32x4*)(qb + f), q1 = *(const f32x4*)(qb + f + 4);
      bf16x8 v;
      v[0] = f2bf(bB0.x - cC0.x + dd0.x * q0.x);
      v[1] = f2bf(bB0.y - cC0.y + dd0.y * q0.y);
      v[2] = f2bf(bB0.z - cC0.z + dd0.z * q0.z);
      v[3] = f2bf(bB0.w - cC0.w + dd0.w * q0.w);
      v[4] = f2bf(bB1.x - cC1.x + dd1.x * q1.x);
      v[5] = f2bf(bB1.y - cC1.y + dd1.y * q1.y);
      v[6] = f2bf(bB1.z - cC1.z + dd1.z * q1.z);
      v[7] = f2bf(bB1.w - cC1.w + dd1.w * q1.w);
      int slot = (f >> 3) ^ (d & 15);
      *(bf16x8*)((char*)smem + d * 256 + slot * 16) = v;
    }
  }

  // ---- u: from preU (mode 2) or in-kernel GEMV fallback ----
  if (mode == 2) {
    if (tid < 128) u2[tid] = uall[(size_t)b * 128 + tid];
    else if (tid < 256) u2[tid] = 0.f;   // u2[128..255] zeroed; loop sums both
  } else {
    int d = tid & 127, fh = tid >> 7;
    const float* arow = w1g + (size_t)d * 512 + fh * 64;
    const float* crow = arow + 256;
    const float* qh   = qb + fh * 64;
    float acc = 0.f;
    #pragma unroll
    for (int i = 0; i < 16; ++i) {
      f32x4 qv = *(const f32x4*)(qh + i * 4);
      f32x4 av = *(const f32x4*)(arow + i * 4);
      f32x4 cv = *(const f32x4*)(crow + i * 4);
      acc += qv.x * (av.x + cv.x) + qv.y * (av.y + cv.y) +
             qv.z * (av.z + cv.z) + qv.w * (av.w + cv.w);
    }
    if (fh == 0) acc += b1g[d];
    u2[fh * 128 + d] = acc;
  }

  __syncthreads();  // barrier 1: M + u2 ready

  // hoist per-lane w2 for its 8 d-columns
  float w2w[8];
  #pragma unroll
  for (int dt = 0; dt < 8; ++dt) w2w[dt] = w2g[dt * 16 + lcol];

  float m_w = -1e9f, den_w = 0.f;
  float accpv[32];
  #pragma unroll
  for (int i = 0; i < 32; ++i) accpv[i] = 0.f;

  #define COMPUTE(TILE, K0, K1)                                              \
    do {                                                                     \
      const int tile_ = (TILE);                                              \
      bf16x8 af[4];                                                          \
      _Pragma("unroll")                                                      \
      for (int ks = 0; ks < 4; ++ks) {                                       \
        af[ks][0] = f2bf(K0[ks].x); af[ks][1] = f2bf(K0[ks].y);              \
        af[ks][2] = f2bf(K0[ks].z); af[ks][3] = f2bf(K0[ks].w);              \
        af[ks][4] = f2bf(K1[ks].x); af[ks][5] = f2bf(K1[ks].y);              \
        af[ks][6] = f2bf(K1[ks].z); af[ks][7] = f2bf(K1[ks].w);              \
      }                                                                      \
      float sj[4] = {0.f, 0.f, 0.f, 0.f};                                    \
      __builtin_amdgcn_s_setprio(1);                                         \
      _Pragma("unroll")                                                      \
      for (int dt = 0; dt < 8; ++dt) {                                       \
        int d_ = dt * 16 + lcol;                                             \
        f32x4 acc = {0.f, 0.f, 0.f, 0.f};                                    \
        _Pragma("unroll")                                                    \
        for (int ks = 0; ks < 4; ++ks) {                                     \
          bf16x8 bfv = *(const bf16x8*)((const char*)smem + d_ * 256 +       \
                                        (((ks * 4 + lrow) ^ (d_ & 15)) << 4)); \
          acc = __builtin_amdgcn_mfma_f32_16x16x32_bf16(af[ks], bfv, acc, 0, 0, 0); \
        }                                                                    \
        float u_d = u2[d_] + u2[128 + d_];                                   \
        float w2d = w2w[dt];                                                 \
        _Pragma("unroll")                                                    \
        for (int j = 0; j < 4; ++j) {                                        \
          float h = acc[j] + u_d;                                            \
          h = (h >= 0.f) ? h : pa * h;                                       \
          sj[j] += h * w2d;                                                  \
        }                                                                    \
      }                                                                      \
      __builtin_amdgcn_s_setprio(0);                                         \
      _Pragma("unroll")                                                      \
      for (int j = 0; j < 4; ++j) sj[j] = sum16(sj[j]);                      \
      unsigned long long mword = tile_ < 4 ? mw0 : tile_ < 8 ? mw1           \
                                 : tile_ < 12 ? mw2 : mw3;                   \
      float mt = -1e30f;                                                     \
      _Pragma("unroll")                                                      \
      for (int j = 0; j < 4; ++j) {                                          \
        int bitp = ((tile_ & 3) << 4) + lrow * 4 + j;                        \
        bool valid = (mword >> bitp) & 1ull;                                 \
        sj[j] = valid ? (sj[j] + b2v) : -1e30f;                              \
        mt = fmaxf(mt, sj[j]);                                               \
      }                                                                      \
      mt = fmaxf(mt, __shfl_xor(mt, 16));                                    \
      mt = fmaxf(mt, __shfl_xor(mt, 32));                                    \
      if (mt > m_w) {  /* exact defer-max */                                 \
        float sc = __expf(m_w - mt);                                         \
        den_w *= sc;                                                         \
        _Pragma("unroll")                                                    \
        for (int i = 0; i < 32; ++i) accpv[i] *= sc;                         \
        m_w = mt;                                                            \
      }                                                                      \
      float wj[4], dsum = 0.f;                                               \
      _Pragma("unroll")                                                      \
      for (int j = 0; j < 4; ++j) { wj[j] = __expf(sj[j] - m_w); dsum += wj[j]; } \
      dsum += __shfl_xor(dsum, 16);                                          \
      dsum += __shfl_xor(dsum, 32);                                          \
      den_w += dsum;                                                         \
      float tmp = (lcol & 2) ? ((lcol & 1) ? wj[3] : wj[2])                  \
                             : ((lcol & 1) ? wj[1] : wj[0]);                 \
      float wtr = __shfl(tmp, ((lcol >> 2) << 4) | (lcol & 3), 64);          \
      _Pragma("unroll")                                                      \
      for (int ks = 0; ks < 4; ++ks) {                                       \
        accpv[ks * 8 + 0] += wtr * K0[ks].x;                                 \
        accpv[ks * 8 + 1] += wtr * K0[ks].y;                                 \
        accpv[ks * 8 + 2] += wtr * K0[ks].z;                                 \
        accpv[ks * 8 + 3] += wtr * K0[ks].w;                                 \
        accpv[ks * 8 + 4] += wtr * K1[ks].x;                                 \
        accpv[ks * 8 + 5] += wtr * K1[ks].y;                                 \
        accpv[ks * 8 + 6] += wtr * K1[ks].z;                                 \
        accpv[ks * 8 + 7] += wtr * K1[ks].w;                                 \
      }                                                                      \
    } while (0)

  // tiles: wid, wid+4, wid+8 for all waves; tile 12 only for wave 0
  COMPUTE(wid, ka0, ka1);
  LOADK(ka0, ka1, wid + 8);          // overlaps next compute
  COMPUTE(wid + 4, kb0, kb1);
  if (wid == 0) LOADK(kb0, kb1, 12);
  COMPUTE(wid + 8, ka0, ka1);
  if (wid == 0) COMPUTE(12, kb0, kb1);

  // ---- fold rows across the 16-lane group (DPP); write per-wave partials ----
  #pragma unroll
  for (int i = 0; i < 32; ++i) accpv[i] = sum16(accpv[i]);
  if (lcol == 0) {
    #pragma unroll
    for (int ks = 0; ks < 4; ++ks) {
      f32x4 a = {accpv[ks * 8 + 0], accpv[ks * 8 + 1], accpv[ks * 8 + 2], accpv[ks * 8 + 3]};
      f32x4 c = {accpv[ks * 8 + 4], accpv[ks * 8 + 5], accpv[ks * 8 + 6], accpv[ks * 8 + 7]};
      *(f32x4*)(outl + wid * 128 + ks * 32 + lrow * 8)     = a;
      *(f32x4*)(outl + wid * 128 + ks * 32 + lrow * 8 + 4) = c;
    }
  }
  if (lane == 0) { red[wid] = m_w; red[4 + wid] = den_w; }

  __syncthreads();  // barrier 2: partials ready

  if (tid < 128) {
    float M = fmaxf(fmaxf(red[0], red[1]), fmaxf(red[2], red[3]));
    float den = 0.f, o = 0.f;
    #pragma unroll
    for (int w = 0; w < 4; ++w) {
      float scw = __expf(red[w] - M);
      den += red[4 + w] * scw;
      o   += outl[w * 128 + tid] * scw;
    }
    float inv = (den > 0.f) ? 1.0f / den : 0.f;
    outg[(size_t)b * 128 + tid] = o * inv;
  }
  #undef COMPUTE
  #undef LOADK
}

}  // namespace

extern "C" void kernel_launch(void* const* d_in, const int* in_sizes, int n_in,
                              void* d_out, int out_size, void* d_ws, size_t ws_size,
                              hipStream_t stream) {
  (void)in_sizes; (void)n_in; (void)out_size;
  const float* q    = (const float*)d_in[0];
  const float* keys = (const float*)d_in[1];
  const void*  mask = d_in[2];
  const float* w1   = (const float*)d_in[3];
  const float* b1   = (const float*)d_in[4];
  const float* pa   = (const float*)d_in[5];
  const float* w2   = (const float*)d_in[6];
  const float* b2   = (const float*)d_in[7];
  float* out = (float*)d_out;

  u32* MD     = (u32*)d_ws;                       // 64 KB packed (Bm-C | Dm)
  float* sTf  = (float*)((char*)d_ws + 65536);    // 64 KB (A+C) f-major
  float* uall = (float*)((char*)d_ws + 131072);   // 1 MB u[B][128]
  int mode = 0;
  if (ws_size >= (size_t)131072 + (size_t)2048 * 128 * 4) mode = 2;
  else if (ws_size >= (size_t)131072)                     mode = 1;

  if (mode >= 1) pre_kernel<<<64, 256, 0, stream>>>(w1, MD, sTf);
  if (mode == 2) preU_kernel<<<2048, 128, 0, stream>>>(q, sTf, b1, uall);
  din_kernel<<<2048, 256, 0, stream>>>(q, keys, mask, w1, b1, pa, w2, b2,
                                       MD, uall, mode, out);
}